// Round 15
// baseline (92.312 us; speedup 1.0000x reference)
//
#include <hip/hip_runtime.h>
#include <hip/hip_bf16.h>
#include <cstddef>
#include <cstdint>

#define N_PIX 4096
#define C_IN  256
#define K_LOW 32
#define LOG2E 1.44269504088896340736f

typedef unsigned int uint;
typedef unsigned short ushort;
typedef __attribute__((ext_vector_type(8))) short short8;
typedef __attribute__((ext_vector_type(16))) float f32x16;

#define DEVI __device__ __forceinline__

union FragU { uint4 u; short8 s; };

DEVI f32x16 mfma32(uint4 a, uint4 b, f32x16 c) {
  FragU A, B; A.u = a; B.u = b;
  return __builtin_amdgcn_mfma_f32_32x32x16_bf16(A.s, B.s, c, 0, 0, 0);
}

DEVI uint cvt_pk_bf16(float lo, float hi) {
  uint r;
  asm("v_cvt_pk_bf16_f32 %0, %1, %2" : "=v"(r) : "v"(lo), "v"(hi));
  return r;
}

DEVI ushort f2b(float v) {
  __hip_bfloat16 h = __float2bfloat16(v);
  return *reinterpret_cast<ushort*>(&h);
}

DEVI float fmax3(float a, float b, float c) {
  float d;
  asm("v_max3_f32 %0, %1, %2, %3" : "=v"(d) : "v"(a), "v"(b), "v"(c));
  return d;
}

DEVI void pswap(uint& a, uint& b) {
  asm("v_permlane32_swap_b32 %0, %1" : "+v"(a), "+v"(b));
}
DEVI void pswapf(float& a, float& b) {
  asm("v_permlane32_swap_b32 %0, %1" : "+v"(a), "+v"(b));
}

DEVI float exp2fast(float x) { return __builtin_amdgcn_exp2f(x); }

#define ROWFN(r, hi) ((((r) & 3)) + 8 * ((r) >> 2) + 4 * (hi))

// ---------------------------------------------------------------------------
// Transpose x (b,c,n) fp32 -> xT (b,n,c) bf16.  Same 256n x 64c tile and
// swizzle as the verified round-10 kernel, but 512-thread blocks: each thread
// covers 32 c-rows (half = tid>>8), raising occupancy 1 -> 2 waves/SIMD.
// + fused weight fp32->bf16 conversion (320 elems per block).
// ---------------------------------------------------------------------------
__global__ __launch_bounds__(512) void xpose_kernel(
    const float* __restrict__ x, ushort* __restrict__ xT,
    const float* __restrict__ fw, const float* __restrict__ gw,
    const float* __restrict__ hw,
    ushort* __restrict__ fw_b, ushort* __restrict__ gw_b, ushort* __restrict__ hw_b)
{
  const int n0 = blockIdx.x * 256;
  const int c0 = blockIdx.y * 64;
  const int b  = blockIdx.z;
  const int tid  = threadIdx.x;
  const int nidx = tid & 255;
  const int half = tid >> 8;      // 0..1: which 32 of the 64 c-rows

  __shared__ uint xt[256 * 32];

  const float* src = x + ((size_t)b * C_IN + c0 + half * 32) * N_PIX + n0 + nidx;
  #pragma unroll
  for (int r8 = 0; r8 < 4; ++r8) {
    float v0 = src[(size_t)(r8 * 8 + 0) * N_PIX], v1 = src[(size_t)(r8 * 8 + 1) * N_PIX];
    float v2 = src[(size_t)(r8 * 8 + 2) * N_PIX], v3 = src[(size_t)(r8 * 8 + 3) * N_PIX];
    float v4 = src[(size_t)(r8 * 8 + 4) * N_PIX], v5 = src[(size_t)(r8 * 8 + 5) * N_PIX];
    float v6 = src[(size_t)(r8 * 8 + 6) * N_PIX], v7 = src[(size_t)(r8 * 8 + 7) * N_PIX];
    uint4 pkd = make_uint4(cvt_pk_bf16(v0, v1), cvt_pk_bf16(v2, v3),
                           cvt_pk_bf16(v4, v5), cvt_pk_bf16(v6, v7));
    *(uint4*)&xt[nidx * 32 + ((half * 16 + r8 * 4) ^ (nidx & 28))] = pkd;
  }
  __syncthreads();
  #pragma unroll
  for (int it = 0; it < 4; ++it) {
    int idx = it * 512 + tid;
    int n = idx >> 3, q4 = idx & 7;
    uint4 v = *(uint4*)&xt[n * 32 + ((q4 * 4) ^ (n & 28))];
    *(uint4*)(xT + ((size_t)b * N_PIX + n0 + n) * C_IN + c0 + q4 * 8) = v;
  }

  // fused weight conversion: 256 blocks x 320 elems = 81920 = 8192+8192+65536
  {
    int bl = (b * 4 + blockIdx.y) * 16 + blockIdx.x;   // 0..255
    int base = bl * 320;
    for (int i = base + tid; i < base + 320; i += 512) {
      if (i < 8192)        fw_b[i]         = f2b(fw[i]);
      else if (i < 16384)  gw_b[i - 8192]  = f2b(gw[i - 8192]);
      else                 hw_b[i - 16384] = f2b(hw[i - 16384]);
    }
  }
}

// ---------------------------------------------------------------------------
// Projection GEMM, pure global-fragment MFMA (no LDS).  High-occupancy
// UNPAIRED version: deletion-diff from the verified round-10 proj (second
// n-subtile xr1/acc1 removed), grid (10 rt, 32 nt, 4 b) = 1280 blocks x
// 4 waves, each wave 32 n-rows x 32 output rows, acc = 16 AGPR (~60 regs
// total -> 5 waves/SIMD from the 5120-wave grid).  Math per output element
// (fragment contents, accumulation order, LOG2E on f) bit-identical.
//   rt 0: f (scaled LOG2E on store)   rt 1: g      (A-op = x)
//   rt 2..9: h rows (rt-2)*32                      (A-op = w)
// ---------------------------------------------------------------------------
__global__ __launch_bounds__(256) void proj_kernel(
    const ushort* __restrict__ xT,
    const ushort* __restrict__ fw_b, const ushort* __restrict__ gw_b,
    const ushort* __restrict__ hw_b,
    const float* __restrict__ fb, const float* __restrict__ gb,
    const float* __restrict__ hb,
    ushort* __restrict__ f_t, ushort* __restrict__ g_t, ushort* __restrict__ h_f)
{
  const int rt  = blockIdx.x;
  const int b   = blockIdx.z;
  const int tid = threadIdx.x;
  const int w    = tid >> 6;            // 0..3
  const int lane = tid & 63;
  const int hi   = lane >> 5;
  const int c31  = lane & 31;
  const int n0   = blockIdx.y * 128 + w * 32;   // 32 n-rows per wave

  const ushort* xTb = xT + (size_t)b * N_PIX * C_IN;
  const ushort* xr0 = xTb + (size_t)(n0 + c31) * C_IN;

  f32x16 acc0;
  #pragma unroll
  for (int r = 0; r < 16; ++r) acc0[r] = 0.f;

  if (rt < 2) {
    const ushort* wb = (rt == 0) ? fw_b : gw_b;
    const ushort* wr = wb + (size_t)c31 * C_IN;
    #pragma unroll
    for (int ks = 0; ks < 16; ++ks) {
      const int koff = ks * 16 + hi * 8;
      uint4 x0 = *(const uint4*)(xr0 + koff);
      uint4 wv = *(const uint4*)(wr + koff);
      acc0 = mfma32(x0, wv, acc0);
    }
    const float* bias = (rt == 0) ? fb : gb;
    ushort* dst = (rt == 0) ? f_t : g_t;
    const float scl = (rt == 0) ? LOG2E : 1.0f;   // fold log2e into keys (f)
    float bv = bias[c31];
    #pragma unroll
    for (int r = 0; r < 16; ++r) {
      int n = n0 + ROWFN(r, hi);
      dst[((size_t)b * N_PIX + n) * K_LOW + c31] = f2b((acc0[r] + bv) * scl);
    }
  } else {
    const ushort* wr = hw_b + (size_t)((rt - 2) * 32 + c31) * C_IN;
    #pragma unroll
    for (int ks = 0; ks < 16; ++ks) {
      const int koff = ks * 16 + hi * 8;
      uint4 x0 = *(const uint4*)(xr0 + koff);
      uint4 wv = *(const uint4*)(wr + koff);
      acc0 = mfma32(wv, x0, acc0);
    }
    const int I = n0 >> 5;
    #pragma unroll
    for (int r = 0; r < 16; ++r) {
      int c = (rt - 2) * 32 + ROWFN(r, hi);
      h_f[((size_t)(b * 128 + I) * C_IN + c) * 32 + c31] = f2b(acc0[r] + hb[c]);
    }
  }
}

// ---------------------------------------------------------------------------
// Flash attention, MFMA 32x32x16 bf16, fp32 accum.  (round-14 verbatim:
// exp2 softmax with f pre-scaled by log2e; load order fA -> QK -> hA.)
// Partition: ws=w&1 (128-ch slice), kg=w>>1 (4-way key split).
// ---------------------------------------------------------------------------
__global__ __launch_bounds__(512) void attn_kernel(
    const ushort* __restrict__ f_t,   // (b, n, 32) keys (pre-scaled by log2e)
    const ushort* __restrict__ g_t,   // (b, n, 32) queries
    const ushort* __restrict__ h_f,   // (b, n>>5, c, 32) values (tiled)
    const float* __restrict__ t_in,   // (b, c, n)
    const float* __restrict__ gamma_p,
    float* __restrict__ out)          // (b, c, n)
{
  const int bid = blockIdx.x;
  const int b   = (bid >> 1) & 3;
  const int q0  = ((bid >> 3) * 2 + (bid & 1)) * 64;
  const int tid = threadIdx.x;
  const int w    = tid >> 6;
  const int lane = tid & 63;
  const int hi   = lane >> 5;
  const int c31  = lane & 31;
  const int ws   = w & 1;
  const int kg   = w >> 1;

  __shared__ float smem[8704];   // [0,8192): merge buf, [8192,8704): m/l

  uint4 gB[2][2];
  #pragma unroll
  for (int kh = 0; kh < 2; ++kh)
    #pragma unroll
    for (int jn = 0; jn < 2; ++jn)
      gB[kh][jn] = *(const uint4*)(g_t +
          ((size_t)b * N_PIX + q0 + jn * 32 + c31) * K_LOW + kh * 16 + hi * 8);

  f32x16 acc[4][2];   // [mi][jn]
  #pragma unroll
  for (int mi = 0; mi < 4; ++mi)
    #pragma unroll
    for (int jn = 0; jn < 2; ++jn)
      #pragma unroll
      for (int r = 0; r < 16; ++r) acc[mi][jn][r] = 0.f;

  float m0 = -1e30f, m1 = -1e30f, l0 = 0.f, l1 = 0.f;

  const ushort* fr = f_t + (size_t)b * N_PIX * K_LOW + ((size_t)kg * 1024 + c31) * K_LOW + hi * 8;
  const ushort* hp = h_f + (size_t)b * 128 * C_IN * 32 + (size_t)kg * 32 * C_IN * 32
                     + (size_t)(ws * 128 + c31) * 32;

  #pragma unroll 1
  for (int t = 0; t < 32; ++t) {
    // key fragments first: QK waits only on these two loads
    uint4 fA0 = *(const uint4*)(fr);
    uint4 fA1 = *(const uint4*)(fr + 16);

    // QK^T (swapped): S^T[i][j]  (already log2-scaled via f)
    f32x16 s0, s1;
    #pragma unroll
    for (int r = 0; r < 16; ++r) { s0[r] = 0.f; s1[r] = 0.f; }
    s0 = mfma32(fA0, gB[0][0], s0);
    s0 = mfma32(fA1, gB[1][0], s0);
    s1 = mfma32(fA0, gB[0][1], s1);
    s1 = mfma32(fA1, gB[1][1], s1);

    // value fragments issued here: stay in flight under softmax, drain at PV
    uint4 hA[2][4];
    #pragma unroll
    for (int kh = 0; kh < 2; ++kh)
      #pragma unroll
      for (int mi = 0; mi < 4; ++mi)
        hA[kh][mi] = *(const uint4*)(hp + mi * 1024 + kh * 16 + hi * 8);

    // row-max over i: max3 chain + cross-half permlane swap
    float mx0 = fmax3(s0[0], s0[1], s0[2]);
    mx0 = fmax3(mx0, s0[3], s0[4]);   mx0 = fmax3(mx0, s0[5], s0[6]);
    mx0 = fmax3(mx0, s0[7], s0[8]);   mx0 = fmax3(mx0, s0[9], s0[10]);
    mx0 = fmax3(mx0, s0[11], s0[12]); mx0 = fmax3(mx0, s0[13], s0[14]);
    mx0 = fmaxf(mx0, s0[15]);
    float mx1 = fmax3(s1[0], s1[1], s1[2]);
    mx1 = fmax3(mx1, s1[3], s1[4]);   mx1 = fmax3(mx1, s1[5], s1[6]);
    mx1 = fmax3(mx1, s1[7], s1[8]);   mx1 = fmax3(mx1, s1[9], s1[10]);
    mx1 = fmax3(mx1, s1[11], s1[12]); mx1 = fmax3(mx1, s1[13], s1[14]);
    mx1 = fmaxf(mx1, s1[15]);
    { float a = mx0, bb = mx0; pswapf(a, bb); mx0 = fmaxf(a, bb); }
    { float a = mx1, bb = mx1; pswapf(a, bb); mx1 = fmaxf(a, bb); }

    // defer-max rescale (threshold 8 in log2 units -> P <= 256)
    bool need = (mx0 > m0 + 8.f) || (mx1 > m1 + 8.f);
    if (__ballot(need)) {
      float mn0 = fmaxf(m0, mx0), mn1 = fmaxf(m1, mx1);
      float sc0 = exp2fast(m0 - mn0), sc1 = exp2fast(m1 - mn1);
      #pragma unroll
      for (int mi = 0; mi < 4; ++mi)
        #pragma unroll
        for (int r = 0; r < 16; ++r) {
          acc[mi][0][r] *= sc0;
          acc[mi][1][r] *= sc1;
        }
      l0 *= sc0; l1 *= sc1; m0 = mn0; m1 = mn1;
    }

    // p = exp2(s - m) in place, tree sums
    #pragma unroll
    for (int r = 0; r < 16; ++r) {
      s0[r] = exp2fast(s0[r] - m0);
      s1[r] = exp2fast(s1[r] - m1);
    }
    {
      float u0[4], u1[4];
      #pragma unroll
      for (int q = 0; q < 4; ++q) {
        u0[q] = (s0[4*q] + s0[4*q+1]) + (s0[4*q+2] + s0[4*q+3]);
        u1[q] = (s1[4*q] + s1[4*q+1]) + (s1[4*q+2] + s1[4*q+3]);
      }
      float sum0 = (u0[0] + u0[1]) + (u0[2] + u0[3]);
      float sum1 = (u1[0] + u1[1]) + (u1[2] + u1[3]);
      { float a = sum0, bb = sum0; pswapf(a, bb); sum0 = a + bb; }
      { float a = sum1, bb = sum1; pswapf(a, bb); sum1 = a + bb; }
      l0 += sum0; l1 += sum1;
    }

    // pack P -> bf16 B-fragments via cvt_pk + permlane32_swap
    uint4 pB[2][2];
    #pragma unroll
    for (int jn = 0; jn < 2; ++jn) {
      const f32x16& p = jn ? s1 : s0;
      uint k0 = cvt_pk_bf16(p[0],  p[1]),  k1 = cvt_pk_bf16(p[2],  p[3]);
      uint k2 = cvt_pk_bf16(p[4],  p[5]),  k3 = cvt_pk_bf16(p[6],  p[7]);
      uint k4 = cvt_pk_bf16(p[8],  p[9]),  k5 = cvt_pk_bf16(p[10], p[11]);
      uint k6 = cvt_pk_bf16(p[12], p[13]), k7 = cvt_pk_bf16(p[14], p[15]);
      pswap(k0, k2); pswap(k1, k3);
      pswap(k4, k6); pswap(k5, k7);
      pB[0][jn] = make_uint4(k0, k1, k2, k3);
      pB[1][jn] = make_uint4(k4, k5, k6, k7);
    }

    // PV: accT[c][j] += H^T x P^T
    #pragma unroll
    for (int kh = 0; kh < 2; ++kh)
      #pragma unroll
      for (int mi = 0; mi < 4; ++mi)
        #pragma unroll
        for (int jn = 0; jn < 2; ++jn)
          acc[mi][jn] = mfma32(hA[kh][mi], pB[kh][jn], acc[mi][jn]);

    fr += 32 * K_LOW;
    hp += C_IN * 32;
  }

  // ---- m/l merge across kg ----
  __syncthreads();
  if (ws == 0 && lane < 32) {
    smem[8192 + (kg * 2 + 0) * 32 + c31] = m0;
    smem[8448 + (kg * 2 + 0) * 32 + c31] = l0;
    smem[8192 + (kg * 2 + 1) * 32 + c31] = m1;
    smem[8448 + (kg * 2 + 1) * 32 + c31] = l1;
  }
  __syncthreads();

  float mk0[4], lk0[4], mk1[4], lk1[4];
  #pragma unroll
  for (int k = 0; k < 4; ++k) {
    mk0[k] = smem[8192 + (k * 2 + 0) * 32 + c31];
    lk0[k] = smem[8448 + (k * 2 + 0) * 32 + c31];
    mk1[k] = smem[8192 + (k * 2 + 1) * 32 + c31];
    lk1[k] = smem[8448 + (k * 2 + 1) * 32 + c31];
  }
  float mf0 = fmax3(fmax3(mk0[0], mk0[1], mk0[2]), mk0[3], -1e30f);
  float mf1 = fmax3(fmax3(mk1[0], mk1[1], mk1[2]), mk1[3], -1e30f);
  float lf0 = 0.f, lf1 = 0.f;
  #pragma unroll
  for (int k = 0; k < 4; ++k) {
    lf0 += lk0[k] * exp2fast(mk0[k] - mf0);
    lf1 += lk1[k] * exp2fast(mk1[k] - mf1);
  }
  float a0 = exp2fast(m0 - mf0), a1 = exp2fast(m1 - mf1);
  #pragma unroll
  for (int mi = 0; mi < 4; ++mi)
    #pragma unroll
    for (int r = 0; r < 16; ++r) {
      acc[mi][0][r] *= a0;
      acc[mi][1][r] *= a1;
    }

  // ---- acc merge across kg (tree: kg0+=kg1, kg2+=kg3, kg0+=kg2),
  //      chunked by (jn, mi-half)  (round-3 verbatim) ----
  #pragma unroll
  for (int jn = 0; jn < 2; ++jn) {
    #pragma unroll
    for (int mh = 0; mh < 2; ++mh) {
      const int base0 = ((kg >> 1) * 2 + ws) * 2048;
      const int baseA = (0 * 2 + ws) * 2048;
      if (kg & 1) {
        #pragma unroll
        for (int mi2 = 0; mi2 < 2; ++mi2)
          #pragma unroll
          for (int r = 0; r < 16; ++r)
            smem[base0 + (mi2 * 32 + ROWFN(r, hi)) * 32 + c31] = acc[mh * 2 + mi2][jn][r];
      }
      __syncthreads();
      if (!(kg & 1)) {
        #pragma unroll
        for (int mi2 = 0; mi2 < 2; ++mi2)
          #pragma unroll
          for (int r = 0; r < 16; ++r)
            acc[mh * 2 + mi2][jn][r] += smem[base0 + (mi2 * 32 + ROWFN(r, hi)) * 32 + c31];
      }
      __syncthreads();
      if (kg == 2) {
        #pragma unroll
        for (int mi2 = 0; mi2 < 2; ++mi2)
          #pragma unroll
          for (int r = 0; r < 16; ++r)
            smem[baseA + (mi2 * 32 + ROWFN(r, hi)) * 32 + c31] = acc[mh * 2 + mi2][jn][r];
      }
      __syncthreads();
      if (kg == 0) {
        #pragma unroll
        for (int mi2 = 0; mi2 < 2; ++mi2)
          #pragma unroll
          for (int r = 0; r < 16; ++r)
            acc[mh * 2 + mi2][jn][r] += smem[baseA + (mi2 * 32 + ROWFN(r, hi)) * 32 + c31];
      }
      __syncthreads();
    }
  }

  if (kg == 0) {
    const float ga = gamma_p[0];
    float inv0 = ga / lf0, inv1 = ga / lf1;
    #pragma unroll
    for (int mi = 0; mi < 4; ++mi)
      #pragma unroll
      for (int jn = 0; jn < 2; ++jn) {
        float inv = jn ? inv1 : inv0;
        #pragma unroll
        for (int r = 0; r < 16; ++r) {
          int c = ws * 128 + mi * 32 + ROWFN(r, hi);
          int j = q0 + jn * 32 + c31;
          size_t off = ((size_t)b * C_IN + c) * N_PIX + j;
          out[off] = acc[mi][jn][r] * inv + t_in[off];
        }
      }
  }
}

extern "C" void kernel_launch(void* const* d_in, const int* in_sizes, int n_in,
                              void* d_out, int out_size, void* d_ws, size_t ws_size,
                              hipStream_t stream) {
  const float* t_in  = (const float*)d_in[0];
  const float* fw    = (const float*)d_in[1];
  const float* fb    = (const float*)d_in[2];
  const float* gw    = (const float*)d_in[3];
  const float* gb    = (const float*)d_in[4];
  const float* hw    = (const float*)d_in[5];
  const float* hb    = (const float*)d_in[6];
  const float* gamma = (const float*)d_in[7];
  float* out = (float*)d_out;

  char* ws = (char*)d_ws;
  ushort* fw_b = (ushort*)(ws);                    // 16 KB
  ushort* gw_b = (ushort*)(ws + 16384);            // 16 KB
  ushort* hw_b = (ushort*)(ws + 32768);            // 128 KB
  ushort* f_t  = (ushort*)(ws + 163840);           // 1 MB  (4,4096,32)
  ushort* g_t  = (ushort*)(ws + 1212416);          // 1 MB
  ushort* h_f  = (ushort*)(ws + 2260992);          // 8 MB  (4,128,256,32)
  ushort* xT   = (ushort*)(ws + 10649600);         // 8 MB

  xpose_kernel<<<dim3(16, 4, 4), 512, 0, stream>>>(
      t_in, xT, fw, gw, hw, fw_b, gw_b, hw_b);
  proj_kernel<<<dim3(10, 32, 4), 256, 0, stream>>>(
      xT, fw_b, gw_b, hw_b, fb, gb, hb, f_t, g_t, h_f);
  attn_kernel<<<dim3(256), 512, 0, stream>>>(
      f_t, g_t, h_f, t_in, gamma, out);
}

// Round 16
// 88.915 us; speedup vs baseline: 1.0382x; 1.0382x over previous
//
#include <hip/hip_runtime.h>
#include <hip/hip_bf16.h>
#include <cstddef>
#include <cstdint>

#define N_PIX 4096
#define C_IN  256
#define K_LOW 32
#define LOG2E 1.44269504088896340736f

typedef unsigned int uint;
typedef unsigned short ushort;
typedef __attribute__((ext_vector_type(8))) short short8;
typedef __attribute__((ext_vector_type(16))) float f32x16;

#define DEVI __device__ __forceinline__

union FragU { uint4 u; short8 s; };

DEVI f32x16 mfma32(uint4 a, uint4 b, f32x16 c) {
  FragU A, B; A.u = a; B.u = b;
  return __builtin_amdgcn_mfma_f32_32x32x16_bf16(A.s, B.s, c, 0, 0, 0);
}

DEVI uint cvt_pk_bf16(float lo, float hi) {
  uint r;
  asm("v_cvt_pk_bf16_f32 %0, %1, %2" : "=v"(r) : "v"(lo), "v"(hi));
  return r;
}

DEVI ushort f2b(float v) {
  __hip_bfloat16 h = __float2bfloat16(v);
  return *reinterpret_cast<ushort*>(&h);
}

DEVI float fmax3(float a, float b, float c) {
  float d;
  asm("v_max3_f32 %0, %1, %2, %3" : "=v"(d) : "v"(a), "v"(b), "v"(c));
  return d;
}

DEVI void pswap(uint& a, uint& b) {
  asm("v_permlane32_swap_b32 %0, %1" : "+v"(a), "+v"(b));
}
DEVI void pswapf(float& a, float& b) {
  asm("v_permlane32_swap_b32 %0, %1" : "+v"(a), "+v"(b));
}

DEVI float exp2fast(float x) { return __builtin_amdgcn_exp2f(x); }

#define ROWFN(r, hi) ((((r) & 3)) + 8 * ((r) >> 2) + 4 * (hi))

// ---------------------------------------------------------------------------
// Transpose x (b,c,n) fp32 -> xT (b,n,c) bf16.  (round-10 verbatim)
// + fused weight fp32->bf16 conversion (320 elems per block).
// ---------------------------------------------------------------------------
__global__ __launch_bounds__(256) void xpose_kernel(
    const float* __restrict__ x, ushort* __restrict__ xT,
    const float* __restrict__ fw, const float* __restrict__ gw,
    const float* __restrict__ hw,
    ushort* __restrict__ fw_b, ushort* __restrict__ gw_b, ushort* __restrict__ hw_b)
{
  const int n0 = blockIdx.x * 256;
  const int c0 = blockIdx.y * 64;
  const int b  = blockIdx.z;
  const int tid = threadIdx.x;

  __shared__ uint xt[256 * 32];

  const float* src = x + ((size_t)b * C_IN + c0) * N_PIX + n0 + tid;
  #pragma unroll
  for (int r8 = 0; r8 < 8; ++r8) {
    float v0 = src[(size_t)(r8 * 8 + 0) * N_PIX], v1 = src[(size_t)(r8 * 8 + 1) * N_PIX];
    float v2 = src[(size_t)(r8 * 8 + 2) * N_PIX], v3 = src[(size_t)(r8 * 8 + 3) * N_PIX];
    float v4 = src[(size_t)(r8 * 8 + 4) * N_PIX], v5 = src[(size_t)(r8 * 8 + 5) * N_PIX];
    float v6 = src[(size_t)(r8 * 8 + 6) * N_PIX], v7 = src[(size_t)(r8 * 8 + 7) * N_PIX];
    uint4 pkd = make_uint4(cvt_pk_bf16(v0, v1), cvt_pk_bf16(v2, v3),
                           cvt_pk_bf16(v4, v5), cvt_pk_bf16(v6, v7));
    *(uint4*)&xt[tid * 32 + ((r8 * 4) ^ (tid & 28))] = pkd;
  }
  __syncthreads();
  #pragma unroll
  for (int it = 0; it < 8; ++it) {
    int idx = it * 256 + tid;
    int n = idx >> 3, q4 = idx & 7;
    uint4 v = *(uint4*)&xt[n * 32 + ((q4 * 4) ^ (n & 28))];
    *(uint4*)(xT + ((size_t)b * N_PIX + n0 + n) * C_IN + c0 + q4 * 8) = v;
  }

  // fused weight conversion: 256 blocks x 320 elems = 81920 = 8192+8192+65536
  {
    int bl = (b * 4 + blockIdx.y) * 16 + blockIdx.x;   // 0..255
    int base = bl * 320;
    for (int i = base + tid; i < base + 320; i += 256) {
      if (i < 8192)        fw_b[i]         = f2b(fw[i]);
      else if (i < 16384)  gw_b[i - 8192]  = f2b(gw[i - 8192]);
      else                 hw_b[i - 16384] = f2b(hw[i - 16384]);
    }
  }
}

// ---------------------------------------------------------------------------
// Projection GEMM, pure global-fragment MFMA (no LDS).  Row-paired wave body
// (each wave owns 32 n-rows, loads each x fragment ONCE, applies two weight
// fragments -> two 32-row output groups A,B).  256-thread blocks, grid
// (5, 32, 4) = 640 blocks for 2.5 blocks/CU dispatch balance.
//   bp==0:  A = f rows (scaled LOG2E on store), B = g rows   (A-op = x)
//   bp>=1:  A = h rows (bp-1)*64..+31, B = +32..+63          (A-op = w)
// ---------------------------------------------------------------------------
__global__ __launch_bounds__(256) void proj_kernel(
    const ushort* __restrict__ xT,
    const ushort* __restrict__ fw_b, const ushort* __restrict__ gw_b,
    const ushort* __restrict__ hw_b,
    const float* __restrict__ fb, const float* __restrict__ gb,
    const float* __restrict__ hb,
    ushort* __restrict__ f_t, ushort* __restrict__ g_t, ushort* __restrict__ h_f)
{
  const int bp  = blockIdx.x;
  const int b   = blockIdx.z;
  const int tid = threadIdx.x;
  const int w    = tid >> 6;            // 0..3
  const int lane = tid & 63;
  const int hi   = lane >> 5;
  const int c31  = lane & 31;
  const int n0   = blockIdx.y * 128 + w * 32;   // 32 n-rows per wave

  const ushort* xTb = xT + (size_t)b * N_PIX * C_IN;
  const ushort* xr0 = xTb + (size_t)(n0 + c31) * C_IN;

  f32x16 accA, accB;
  #pragma unroll
  for (int r = 0; r < 16; ++r) { accA[r] = 0.f; accB[r] = 0.f; }

  if (bp == 0) {
    const ushort* wrF = fw_b + (size_t)c31 * C_IN;
    const ushort* wrG = gw_b + (size_t)c31 * C_IN;
    #pragma unroll
    for (int ks = 0; ks < 16; ++ks) {
      const int koff = ks * 16 + hi * 8;
      uint4 x0  = *(const uint4*)(xr0 + koff);
      uint4 wvF = *(const uint4*)(wrF + koff);
      uint4 wvG = *(const uint4*)(wrG + koff);
      accA = mfma32(x0, wvF, accA);
      accB = mfma32(x0, wvG, accB);
    }
    float bfv = fb[c31], bgv = gb[c31];
    #pragma unroll
    for (int r = 0; r < 16; ++r) {
      int n = n0 + ROWFN(r, hi);
      f_t[((size_t)b * N_PIX + n) * K_LOW + c31] = f2b((accA[r] + bfv) * LOG2E);
      g_t[((size_t)b * N_PIX + n) * K_LOW + c31] = f2b(accB[r] + bgv);
    }
  } else {
    const ushort* wrA = hw_b + (size_t)((bp - 1) * 64 + c31) * C_IN;
    const ushort* wrB = hw_b + (size_t)((bp - 1) * 64 + 32 + c31) * C_IN;
    #pragma unroll
    for (int ks = 0; ks < 16; ++ks) {
      const int koff = ks * 16 + hi * 8;
      uint4 x0  = *(const uint4*)(xr0 + koff);
      uint4 wvA = *(const uint4*)(wrA + koff);
      uint4 wvB = *(const uint4*)(wrB + koff);
      accA = mfma32(wvA, x0, accA);
      accB = mfma32(wvB, x0, accB);
    }
    const int I = n0 >> 5;
    #pragma unroll
    for (int r = 0; r < 16; ++r) {
      int ca = (bp - 1) * 64 + ROWFN(r, hi);
      int cb = ca + 32;
      h_f[((size_t)(b * 128 + I) * C_IN + ca) * 32 + c31] = f2b(accA[r] + hb[ca]);
      h_f[((size_t)(b * 128 + I) * C_IN + cb) * 32 + c31] = f2b(accB[r] + hb[cb]);
    }
  }
}

// ---------------------------------------------------------------------------
// Flash attention, MFMA 32x32x16 bf16, fp32 accum.  (round-10 verbatim:
// exp2 softmax with f pre-scaled by log2e; load order fA -> QK -> hA.)
// Partition: ws=w&1 (128-ch slice), kg=w>>1 (4-way key split).
// ---------------------------------------------------------------------------
__global__ __launch_bounds__(512) void attn_kernel(
    const ushort* __restrict__ f_t,   // (b, n, 32) keys (pre-scaled by log2e)
    const ushort* __restrict__ g_t,   // (b, n, 32) queries
    const ushort* __restrict__ h_f,   // (b, n>>5, c, 32) values (tiled)
    const float* __restrict__ t_in,   // (b, c, n)
    const float* __restrict__ gamma_p,
    float* __restrict__ out)          // (b, c, n)
{
  const int bid = blockIdx.x;
  const int b   = (bid >> 1) & 3;
  const int q0  = ((bid >> 3) * 2 + (bid & 1)) * 64;
  const int tid = threadIdx.x;
  const int w    = tid >> 6;
  const int lane = tid & 63;
  const int hi   = lane >> 5;
  const int c31  = lane & 31;
  const int ws   = w & 1;
  const int kg   = w >> 1;

  __shared__ float smem[8704];   // [0,8192): merge buf, [8192,8704): m/l

  uint4 gB[2][2];
  #pragma unroll
  for (int kh = 0; kh < 2; ++kh)
    #pragma unroll
    for (int jn = 0; jn < 2; ++jn)
      gB[kh][jn] = *(const uint4*)(g_t +
          ((size_t)b * N_PIX + q0 + jn * 32 + c31) * K_LOW + kh * 16 + hi * 8);

  f32x16 acc[4][2];   // [mi][jn]
  #pragma unroll
  for (int mi = 0; mi < 4; ++mi)
    #pragma unroll
    for (int jn = 0; jn < 2; ++jn)
      #pragma unroll
      for (int r = 0; r < 16; ++r) acc[mi][jn][r] = 0.f;

  float m0 = -1e30f, m1 = -1e30f, l0 = 0.f, l1 = 0.f;

  const ushort* fr = f_t + (size_t)b * N_PIX * K_LOW + ((size_t)kg * 1024 + c31) * K_LOW + hi * 8;
  const ushort* hp = h_f + (size_t)b * 128 * C_IN * 32 + (size_t)kg * 32 * C_IN * 32
                     + (size_t)(ws * 128 + c31) * 32;

  #pragma unroll 1
  for (int t = 0; t < 32; ++t) {
    // key fragments first: QK waits only on these two loads
    uint4 fA0 = *(const uint4*)(fr);
    uint4 fA1 = *(const uint4*)(fr + 16);

    // QK^T (swapped): S^T[i][j]  (already log2-scaled via f)
    f32x16 s0, s1;
    #pragma unroll
    for (int r = 0; r < 16; ++r) { s0[r] = 0.f; s1[r] = 0.f; }
    s0 = mfma32(fA0, gB[0][0], s0);
    s0 = mfma32(fA1, gB[1][0], s0);
    s1 = mfma32(fA0, gB[0][1], s1);
    s1 = mfma32(fA1, gB[1][1], s1);

    // value fragments issued here: stay in flight under softmax, drain at PV
    uint4 hA[2][4];
    #pragma unroll
    for (int kh = 0; kh < 2; ++kh)
      #pragma unroll
      for (int mi = 0; mi < 4; ++mi)
        hA[kh][mi] = *(const uint4*)(hp + mi * 1024 + kh * 16 + hi * 8);

    // row-max over i: max3 chain + cross-half permlane swap
    float mx0 = fmax3(s0[0], s0[1], s0[2]);
    mx0 = fmax3(mx0, s0[3], s0[4]);   mx0 = fmax3(mx0, s0[5], s0[6]);
    mx0 = fmax3(mx0, s0[7], s0[8]);   mx0 = fmax3(mx0, s0[9], s0[10]);
    mx0 = fmax3(mx0, s0[11], s0[12]); mx0 = fmax3(mx0, s0[13], s0[14]);
    mx0 = fmaxf(mx0, s0[15]);
    float mx1 = fmax3(s1[0], s1[1], s1[2]);
    mx1 = fmax3(mx1, s1[3], s1[4]);   mx1 = fmax3(mx1, s1[5], s1[6]);
    mx1 = fmax3(mx1, s1[7], s1[8]);   mx1 = fmax3(mx1, s1[9], s1[10]);
    mx1 = fmax3(mx1, s1[11], s1[12]); mx1 = fmax3(mx1, s1[13], s1[14]);
    mx1 = fmaxf(mx1, s1[15]);
    { float a = mx0, bb = mx0; pswapf(a, bb); mx0 = fmaxf(a, bb); }
    { float a = mx1, bb = mx1; pswapf(a, bb); mx1 = fmaxf(a, bb); }

    // defer-max rescale (threshold 8 in log2 units -> P <= 256)
    bool need = (mx0 > m0 + 8.f) || (mx1 > m1 + 8.f);
    if (__ballot(need)) {
      float mn0 = fmaxf(m0, mx0), mn1 = fmaxf(m1, mx1);
      float sc0 = exp2fast(m0 - mn0), sc1 = exp2fast(m1 - mn1);
      #pragma unroll
      for (int mi = 0; mi < 4; ++mi)
        #pragma unroll
        for (int r = 0; r < 16; ++r) {
          acc[mi][0][r] *= sc0;
          acc[mi][1][r] *= sc1;
        }
      l0 *= sc0; l1 *= sc1; m0 = mn0; m1 = mn1;
    }

    // p = exp2(s - m) in place, tree sums
    #pragma unroll
    for (int r = 0; r < 16; ++r) {
      s0[r] = exp2fast(s0[r] - m0);
      s1[r] = exp2fast(s1[r] - m1);
    }
    {
      float u0[4], u1[4];
      #pragma unroll
      for (int q = 0; q < 4; ++q) {
        u0[q] = (s0[4*q] + s0[4*q+1]) + (s0[4*q+2] + s0[4*q+3]);
        u1[q] = (s1[4*q] + s1[4*q+1]) + (s1[4*q+2] + s1[4*q+3]);
      }
      float sum0 = (u0[0] + u0[1]) + (u0[2] + u0[3]);
      float sum1 = (u1[0] + u1[1]) + (u1[2] + u1[3]);
      { float a = sum0, bb = sum0; pswapf(a, bb); sum0 = a + bb; }
      { float a = sum1, bb = sum1; pswapf(a, bb); sum1 = a + bb; }
      l0 += sum0; l1 += sum1;
    }

    // pack P -> bf16 B-fragments via cvt_pk + permlane32_swap
    uint4 pB[2][2];
    #pragma unroll
    for (int jn = 0; jn < 2; ++jn) {
      const f32x16& p = jn ? s1 : s0;
      uint k0 = cvt_pk_bf16(p[0],  p[1]),  k1 = cvt_pk_bf16(p[2],  p[3]);
      uint k2 = cvt_pk_bf16(p[4],  p[5]),  k3 = cvt_pk_bf16(p[6],  p[7]);
      uint k4 = cvt_pk_bf16(p[8],  p[9]),  k5 = cvt_pk_bf16(p[10], p[11]);
      uint k6 = cvt_pk_bf16(p[12], p[13]), k7 = cvt_pk_bf16(p[14], p[15]);
      pswap(k0, k2); pswap(k1, k3);
      pswap(k4, k6); pswap(k5, k7);
      pB[0][jn] = make_uint4(k0, k1, k2, k3);
      pB[1][jn] = make_uint4(k4, k5, k6, k7);
    }

    // PV: accT[c][j] += H^T x P^T
    #pragma unroll
    for (int kh = 0; kh < 2; ++kh)
      #pragma unroll
      for (int mi = 0; mi < 4; ++mi)
        #pragma unroll
        for (int jn = 0; jn < 2; ++jn)
          acc[mi][jn] = mfma32(hA[kh][mi], pB[kh][jn], acc[mi][jn]);

    fr += 32 * K_LOW;
    hp += C_IN * 32;
  }

  // ---- m/l merge across kg ----
  __syncthreads();
  if (ws == 0 && lane < 32) {
    smem[8192 + (kg * 2 + 0) * 32 + c31] = m0;
    smem[8448 + (kg * 2 + 0) * 32 + c31] = l0;
    smem[8192 + (kg * 2 + 1) * 32 + c31] = m1;
    smem[8448 + (kg * 2 + 1) * 32 + c31] = l1;
  }
  __syncthreads();

  float mk0[4], lk0[4], mk1[4], lk1[4];
  #pragma unroll
  for (int k = 0; k < 4; ++k) {
    mk0[k] = smem[8192 + (k * 2 + 0) * 32 + c31];
    lk0[k] = smem[8448 + (k * 2 + 0) * 32 + c31];
    mk1[k] = smem[8192 + (k * 2 + 1) * 32 + c31];
    lk1[k] = smem[8448 + (k * 2 + 1) * 32 + c31];
  }
  float mf0 = fmax3(fmax3(mk0[0], mk0[1], mk0[2]), mk0[3], -1e30f);
  float mf1 = fmax3(fmax3(mk1[0], mk1[1], mk1[2]), mk1[3], -1e30f);
  float lf0 = 0.f, lf1 = 0.f;
  #pragma unroll
  for (int k = 0; k < 4; ++k) {
    lf0 += lk0[k] * exp2fast(mk0[k] - mf0);
    lf1 += lk1[k] * exp2fast(mk1[k] - mf1);
  }
  float a0 = exp2fast(m0 - mf0), a1 = exp2fast(m1 - mf1);
  #pragma unroll
  for (int mi = 0; mi < 4; ++mi)
    #pragma unroll
    for (int r = 0; r < 16; ++r) {
      acc[mi][0][r] *= a0;
      acc[mi][1][r] *= a1;
    }

  // ---- acc merge across kg (tree: kg0+=kg1, kg2+=kg3, kg0+=kg2),
  //      chunked by (jn, mi-half)  (round-3 verbatim) ----
  #pragma unroll
  for (int jn = 0; jn < 2; ++jn) {
    #pragma unroll
    for (int mh = 0; mh < 2; ++mh) {
      const int base0 = ((kg >> 1) * 2 + ws) * 2048;
      const int baseA = (0 * 2 + ws) * 2048;
      if (kg & 1) {
        #pragma unroll
        for (int mi2 = 0; mi2 < 2; ++mi2)
          #pragma unroll
          for (int r = 0; r < 16; ++r)
            smem[base0 + (mi2 * 32 + ROWFN(r, hi)) * 32 + c31] = acc[mh * 2 + mi2][jn][r];
      }
      __syncthreads();
      if (!(kg & 1)) {
        #pragma unroll
        for (int mi2 = 0; mi2 < 2; ++mi2)
          #pragma unroll
          for (int r = 0; r < 16; ++r)
            acc[mh * 2 + mi2][jn][r] += smem[base0 + (mi2 * 32 + ROWFN(r, hi)) * 32 + c31];
      }
      __syncthreads();
      if (kg == 2) {
        #pragma unroll
        for (int mi2 = 0; mi2 < 2; ++mi2)
          #pragma unroll
          for (int r = 0; r < 16; ++r)
            smem[baseA + (mi2 * 32 + ROWFN(r, hi)) * 32 + c31] = acc[mh * 2 + mi2][jn][r];
      }
      __syncthreads();
      if (kg == 0) {
        #pragma unroll
        for (int mi2 = 0; mi2 < 2; ++mi2)
          #pragma unroll
          for (int r = 0; r < 16; ++r)
            acc[mh * 2 + mi2][jn][r] += smem[baseA + (mi2 * 32 + ROWFN(r, hi)) * 32 + c31];
      }
      __syncthreads();
    }
  }

  if (kg == 0) {
    const float ga = gamma_p[0];
    float inv0 = ga / lf0, inv1 = ga / lf1;
    #pragma unroll
    for (int mi = 0; mi < 4; ++mi)
      #pragma unroll
      for (int jn = 0; jn < 2; ++jn) {
        float inv = jn ? inv1 : inv0;
        #pragma unroll
        for (int r = 0; r < 16; ++r) {
          int c = ws * 128 + mi * 32 + ROWFN(r, hi);
          int j = q0 + jn * 32 + c31;
          size_t off = ((size_t)b * C_IN + c) * N_PIX + j;
          out[off] = acc[mi][jn][r] * inv + t_in[off];
        }
      }
  }
}

extern "C" void kernel_launch(void* const* d_in, const int* in_sizes, int n_in,
                              void* d_out, int out_size, void* d_ws, size_t ws_size,
                              hipStream_t stream) {
  const float* t_in  = (const float*)d_in[0];
  const float* fw    = (const float*)d_in[1];
  const float* fb    = (const float*)d_in[2];
  const float* gw    = (const float*)d_in[3];
  const float* gb    = (const float*)d_in[4];
  const float* hw    = (const float*)d_in[5];
  const float* hb    = (const float*)d_in[6];
  const float* gamma = (const float*)d_in[7];
  float* out = (float*)d_out;

  char* ws = (char*)d_ws;
  ushort* fw_b = (ushort*)(ws);                    // 16 KB
  ushort* gw_b = (ushort*)(ws + 16384);            // 16 KB
  ushort* hw_b = (ushort*)(ws + 32768);            // 128 KB
  ushort* f_t  = (ushort*)(ws + 163840);           // 1 MB  (4,4096,32)
  ushort* g_t  = (ushort*)(ws + 1212416);          // 1 MB
  ushort* h_f  = (ushort*)(ws + 2260992);          // 8 MB  (4,128,256,32)
  ushort* xT   = (ushort*)(ws + 10649600);         // 8 MB

  xpose_kernel<<<dim3(16, 4, 4), 256, 0, stream>>>(
      t_in, xT, fw, gw, hw, fw_b, gw_b, hw_b);
  proj_kernel<<<dim3(5, 32, 4), 256, 0, stream>>>(
      xT, fw_b, gw_b, hw_b, fb, gb, hb, f_t, g_t, h_f);
  attn_kernel<<<dim3(256), 512, 0, stream>>>(
      f_t, g_t, h_f, t_in, gamma, out);
}